// Round 5
// baseline (146.012 us; speedup 1.0000x reference)
//
#include <hip/hip_runtime.h>
#include <math.h>

#define NFFT    1024
#define HOP     256
#define NMELS   128
#define NFRAMES 626
#define NPAIRS  313
#define NBATCH  32
#define LSAMP   160000
#define NFREQ   513   // NFFT/2 + 1

struct Bins { int v[NMELS + 2]; };   // 130 ints = 520 B kernarg

// reflect-pad index (np.pad mode='reflect', no edge repeat)
__device__ __forceinline__ int refl(int i) {
    if (i < 0) i = -i;
    else if (i >= LSAMP) i = 2 * LSAMP - 2 - i;
    return i;
}

__device__ __forceinline__ float2 cadd(float2 a, float2 b){return make_float2(a.x+b.x, a.y+b.y);}
__device__ __forceinline__ float2 csub(float2 a, float2 b){return make_float2(a.x-b.x, a.y-b.y);}
__device__ __forceinline__ float2 cmul(float2 a, float2 b){
    return make_float2(fmaf(a.x,b.x,-a.y*b.y), fmaf(a.x,b.y,a.y*b.x));
}
__device__ __forceinline__ float2 cmulnegi(float2 a){return make_float2(a.y, -a.x);}   // a * (-i)

// 16-point DFT, natural order in/out, in-place, registers only.
// Verified: delta input z[a]=d[a-1] -> W16^k; constant input -> delta at 0.
__device__ __forceinline__ void dft16(float2* z) {
    const float2 W1 = make_float2( 0.92387953251f, -0.38268343236f);
    const float2 W2 = make_float2( 0.70710678119f, -0.70710678119f);
    const float2 W3 = make_float2( 0.38268343236f, -0.92387953251f);
    const float2 W6 = make_float2(-0.70710678119f, -0.70710678119f);
    const float2 W9 = make_float2(-0.92387953251f,  0.38268343236f);
    float2 g[16];
    #pragma unroll
    for (int q = 0; q < 4; q++) {           // DFT4 over p of z[4p+q]
        float2 t0=z[q], t1=z[4+q], t2=z[8+q], t3=z[12+q];
        float2 A=cadd(t0,t2), B=csub(t0,t2), C=cadd(t1,t3), D=csub(t1,t3);
        g[q]    = cadd(A,C);
        g[4+q]  = make_float2(B.x + D.y, B.y - D.x);   // B - iD
        g[8+q]  = csub(A,C);
        g[12+q] = make_float2(B.x - D.y, B.y + D.x);   // B + iD
    }
    // twiddles W16^{q*r} on g[4r+q]
    g[4+1] =cmul(g[4+1], W1); g[4+2] =cmul(g[4+2], W2); g[4+3] =cmul(g[4+3], W3);
    g[8+1] =cmul(g[8+1], W2); g[8+2] =cmulnegi(g[8+2]); g[8+3] =cmul(g[8+3], W6);
    g[12+1]=cmul(g[12+1],W3); g[12+2]=cmul(g[12+2],W6);  g[12+3]=cmul(g[12+3],W9);
    #pragma unroll
    for (int r = 0; r < 4; r++) {           // DFT4 over q, out index r+4s
        float2 t0=g[4*r], t1=g[4*r+1], t2=g[4*r+2], t3=g[4*r+3];
        float2 A=cadd(t0,t2), B=csub(t0,t2), C=cadd(t1,t3), D=csub(t1,t3);
        z[r]    = cadd(A,C);
        z[r+4]  = make_float2(B.x + D.y, B.y - D.x);
        z[r+8]  = csub(A,C);
        z[r+12] = make_float2(B.x - D.y, B.y + D.x);
    }
}

// One 64-thread block = one frame pair (two-for-one complex FFT).
// Four-step 1024 = 16 x 16 x 4: each thread owns 16 points in registers,
// 3 in-place LDS exchanges (stride-17 layout = b64 bank floor, no conflicts).
__global__ __launch_bounds__(64)
void fft_mel_kernel(const float* __restrict__ x, float* __restrict__ mel,
                    Bins bins) {
    __shared__ float2 buf[1088];          // single in-place exchange buffer
    __shared__ float  spec[2 * NFREQ];
    __shared__ float2 twb[64];            // W_1024^u

    const int u = threadIdx.x;            // 0..63
    const int p = blockIdx.x;             // frame-pair 0..312
    const int b = blockIdx.y;             // batch row

    { float s, c; __sincosf(-(float)M_PI * (float)u * (1.0f/512.0f), &s, &c);
      twb[u] = make_float2(c, s); }

    // load frame pair (reflect pad): z[n] = fr0[n] + i*fr1[n]
    const float* xb = x + (size_t)b * LSAMP;
    const int base = 512 * p - 512;
    for (int i = u; i < 1024; i += 64) {
        float re = xb[refl(base + i)];
        float im = xb[refl(base + i + 256)];
        buf[i] = make_float2(re, im);
    }
    __syncthreads();

    float2 z[16];

    // ---- stage 1: thread u = outer residue b. DFT16 over a of z[64a+u],
    //      twiddle W_1024^{u*k1}, store at e1 = 17u + k1.
    #pragma unroll
    for (int a = 0; a < 16; a++) z[a] = buf[64*a + u];
    dft16(z);
    {
        float2 w1 = twb[u], wk = w1;
        #pragma unroll
        for (int k = 1; k < 16; k++) { z[k] = cmul(z[k], wk); wk = cmul(wk, w1); }
    }
    __syncthreads();
    #pragma unroll
    for (int k = 0; k < 16; k++) buf[17*u + k] = z[k];
    __syncthreads();

    // ---- stage 2: u -> (k1 = u>>2, bp = u&3). DFT16 over a' of Z[k1, 4a'+bp],
    //      twiddle W_64^{bp*k2a} = W_1024^{16*bp*k2a}, store e2 = 68*k2a + 17*bp + k1.
    const int k1 = u >> 2, bp = u & 3;
    #pragma unroll
    for (int a = 0; a < 16; a++) z[a] = buf[68*a + 17*bp + k1];
    dft16(z);
    {
        float2 w1 = twb[16*bp], wk = w1;
        #pragma unroll
        for (int k = 1; k < 16; k++) { z[k] = cmul(z[k], wk); wk = cmul(wk, w1); }
    }
    __syncthreads();
    #pragma unroll
    for (int k = 0; k < 16; k++) buf[68*k + 17*bp + k1] = z[k];
    __syncthreads();

    // ---- stage 3: DFT4 over bp for each (k1, k2a); X[k1 + 16*k2a + 256*k2b].
    #pragma unroll
    for (int j = 0; j < 4; j++) {
        const int c = 64*j + u;
        const int kk1 = c & 15, k2a = c >> 4;
        #pragma unroll
        for (int bq = 0; bq < 4; bq++) z[4*j + bq] = buf[68*k2a + 17*bq + kk1];
    }
    __syncthreads();
    #pragma unroll
    for (int j = 0; j < 4; j++) {
        const int kbase = u + 64*j;       // = (c&15) + 16*(c>>4), c = 64j+u
        float2 t0=z[4*j], t1=z[4*j+1], t2=z[4*j+2], t3=z[4*j+3];
        float2 A=cadd(t0,t2), B=csub(t0,t2), C=cadd(t1,t3), D=csub(t1,t3);
        buf[kbase]       = cadd(A,C);
        buf[kbase + 256] = make_float2(B.x + D.y, B.y - D.x);
        buf[kbase + 512] = csub(A,C);
        buf[kbase + 768] = make_float2(B.x - D.y, B.y + D.x);
    }
    __syncthreads();

    // ---- unpack two-for-one + magnitude
    for (int k = u; k < NFREQ; k += 64) {
        const int nk = (1024 - k) & 1023;
        float2 Zk = buf[k], Zn = buf[nk];
        float ar = Zk.x + Zn.x, ai = Zk.y - Zn.y;
        float br = Zk.y + Zn.y, bi = Zn.x - Zk.x;
        spec[k]         = 0.5f * sqrtf(ar*ar + ai*ai);
        spec[NFREQ + k] = 0.5f * sqrtf(br*br + bi*bi);
    }
    __syncthreads();

    // ---- sparse mel: iteration i covers a 32-col band (similar widths ->
    //      wave-uniform-ish trip counts); pf split across wave halves.
    const int r = u & 31, pf = u >> 5;
    const float* sp = spec + pf * NFREQ;
    #pragma unroll
    for (int i = 0; i < 4; i++) {
        const int mm = 32*i + r;
        const int a = bins.v[mm], bb = bins.v[mm+1], c = bins.v[mm+2];
        float acc = 0.f;
        if (bb > a) {
            float s = 0.f;
            for (int f = a; f < bb; f++) s = fmaf(sp[f], (float)(f - a), s);
            acc += s / (float)(bb - a);
        }
        if (c > bb) {
            float s = 0.f;
            for (int f = bb; f < c; f++) s = fmaf(sp[f], (float)(c - f), s);
            acc += s / (float)(c - bb);
        }
        mel[((size_t)b * NFRAMES + 2*p + pf) * NMELS + mm] = acc;
    }
}

// ---------------- Fused exact PCEN (single dispatch) ----------------
// Block = (m-octet, batch); threads = (t-group g in [0,16), mr in [0,16)).
// 3-phase affine-scan entirely in LDS: group EMA-from-zero, tiny serial scan
// of 16 group boundaries, replay from exact group-entry M.
#define PG    16
#define GLEN  40    // ceil(626/16); last group has 26 frames

__global__ __launch_bounds__(256)
void pcen_all(const float* __restrict__ mel, float* __restrict__ out) {
    __shared__ float SS[PG * 17];
    __shared__ float MS[PG * 17];
    const int tid = threadIdx.x;
    const int g = tid >> 4, mr = tid & 15;
    const int mq = blockIdx.x;            // 0..7
    const int b  = blockIdx.y;            // 0..31
    const int m  = 16*mq + mr;
    const int t0 = GLEN * g;
    const int tend = (t0 + GLEN < NFRAMES) ? t0 + GLEN : NFRAMES;

    const float* mp = mel + (size_t)b * NFRAMES * NMELS + m;
    float*       op = out + (size_t)b * NFRAMES * NMELS + m;

    // phase A: EMA-from-zero over this group (t=0 seeds exactly)
    float s = 0.f;
    for (int t = t0; t < tend; t++) {
        float v = mp[(size_t)t * NMELS];
        s = (t == 0) ? v : fmaf(0.975f, s, 0.025f * v);
    }
    SS[17*g + mr] = s;
    __syncthreads();

    // phase B: serial scan of 16 group boundaries (16 lanes)
    if (tid < 16) {
        const float D40 = __powf(0.975f, 40.0f);
        float M = 0.f;
        for (int gg = 0; gg < PG; gg++) {
            MS[17*gg + tid] = M;
            M = fmaf(D40, M, SS[17*gg + tid]);
        }
    }
    __syncthreads();

    // phase C: replay from exact group-entry state
    float M = MS[17*g + mr];
    for (int t = t0; t < tend; t++) {
        float v = mp[(size_t)t * NMELS];
        M = (t == 0) ? v : fmaf(0.975f, M, 0.025f * v);
        float den = __powf(M + 1e-6f, 0.98f);
        op[(size_t)t * NMELS] = sqrtf(v / den + 2.0f) - 1.41421356237f;
    }
}

extern "C" void kernel_launch(void* const* d_in, const int* in_sizes, int n_in,
                              void* d_out, int out_size, void* d_ws, size_t ws_size,
                              hipStream_t stream) {
    const float* x  = (const float*)d_in[0];   // (32, 160000)
    float* mel = (float*)d_ws;                 // (32, 626, 128) f32 scratch
    float* out = (float*)d_out;                // (32, 626, 128)

    // Host-side bin edges, replicating numpy exactly in double.
    Bins bins;
    {
        const double m_max = 2595.0 * log10(1.0 + 8000.0 / 700.0);
        const double step  = m_max / 129.0;
        for (int i = 0; i < NMELS + 2; i++) {
            double mv = (i == NMELS + 1) ? m_max : (double)i * step;
            double f  = 700.0 * (pow(10.0, mv / 2595.0) - 1.0);
            bins.v[i] = (int)floor((double)(NFREQ - 1) * 2.0 * f / 16000.0);
        }
    }

    dim3 grid1(NPAIRS, NBATCH);
    fft_mel_kernel<<<grid1, 64, 0, stream>>>(x, mel, bins);

    dim3 grid2(8, NBATCH);
    pcen_all<<<grid2, 256, 0, stream>>>(mel, out);
}

// Round 6
// 132.830 us; speedup vs baseline: 1.0992x; 1.0992x over previous
//
#include <hip/hip_runtime.h>
#include <math.h>

#define NMELS   128
#define NFRAMES 626
#define NPAIRS  313
#define NBATCH  32
#define LSAMP   160000
#define NFREQ   513                         // 1024/2 + 1
#define PPB     4                           // frame-pairs per block (1 per wave)
#define NBLK    ((NPAIRS + PPB - 1) / PPB)  // 79
#define NCHUNK  NBLK                        // pcen chunk = 8 frames = 1 block

struct Bins { int v[NMELS + 2]; };          // 130 ints = 520 B kernarg

// reflect-pad index (np.pad mode='reflect', no edge repeat)
__device__ __forceinline__ int refl(int i) {
    if (i < 0) i = -i;
    else if (i >= LSAMP) i = 2 * LSAMP - 2 - i;
    return i;
}

__device__ __forceinline__ float2 cadd(float2 a, float2 b){return make_float2(a.x+b.x, a.y+b.y);}
__device__ __forceinline__ float2 csub(float2 a, float2 b){return make_float2(a.x-b.x, a.y-b.y);}
__device__ __forceinline__ float2 cmul(float2 a, float2 b){
    return make_float2(fmaf(a.x,b.x,-a.y*b.y), fmaf(a.x,b.y,a.y*b.x));
}
__device__ __forceinline__ float2 cmulnegi(float2 a){return make_float2(a.y, -a.x);}   // a * (-i)

// 16-point DFT, natural order in/out, registers only (HW-verified in R5).
__device__ __forceinline__ void dft16(float2* z) {
    const float2 W1 = make_float2( 0.92387953251f, -0.38268343236f);
    const float2 W2 = make_float2( 0.70710678119f, -0.70710678119f);
    const float2 W3 = make_float2( 0.38268343236f, -0.92387953251f);
    const float2 W6 = make_float2(-0.70710678119f, -0.70710678119f);
    const float2 W9 = make_float2(-0.92387953251f,  0.38268343236f);
    float2 g[16];
    #pragma unroll
    for (int q = 0; q < 4; q++) {
        float2 t0=z[q], t1=z[4+q], t2=z[8+q], t3=z[12+q];
        float2 A=cadd(t0,t2), B=csub(t0,t2), C=cadd(t1,t3), D=csub(t1,t3);
        g[q]    = cadd(A,C);
        g[4+q]  = make_float2(B.x + D.y, B.y - D.x);
        g[8+q]  = csub(A,C);
        g[12+q] = make_float2(B.x - D.y, B.y + D.x);
    }
    g[4+1] =cmul(g[4+1], W1); g[4+2] =cmul(g[4+2], W2); g[4+3] =cmul(g[4+3], W3);
    g[8+1] =cmul(g[8+1], W2); g[8+2] =cmulnegi(g[8+2]); g[8+3] =cmul(g[8+3], W6);
    g[12+1]=cmul(g[12+1],W3); g[12+2]=cmul(g[12+2],W6);  g[12+3]=cmul(g[12+3],W9);
    #pragma unroll
    for (int r = 0; r < 4; r++) {
        float2 t0=g[4*r], t1=g[4*r+1], t2=g[4*r+2], t3=g[4*r+3];
        float2 A=cadd(t0,t2), B=csub(t0,t2), C=cadd(t1,t3), D=csub(t1,t3);
        z[r]    = cadd(A,C);
        z[r+4]  = make_float2(B.x + D.y, B.y - D.x);
        z[r+8]  = csub(A,C);
        z[r+12] = make_float2(B.x - D.y, B.y + D.x);
    }
}

// 256-thread block = 4 wave-private FFT frame-pairs = 8 frames = 1 pcen chunk.
// Per wave: four-step 1024 = 16x16x4 FFT, 16 pts/lane in regs, 3 in-place LDS
// exchanges in the wave's OWN buffer -> no __syncthreads in the FFT path
// (wave lockstep + in-order DS pipe). Epilogue: stage mel in LDS (aliasing
// wave-0's dead spec), one barrier, compute pcen chunk-sum S.
__global__ __launch_bounds__(256)
void fft_mel_kernel(const float* __restrict__ x, float* __restrict__ mel,
                    float* __restrict__ S, Bins bins) {
    __shared__ float2 wbuf[PPB][1088];      // 34816 B (17-stride padded layout)
    __shared__ float  wspec[PPB][1026];     // 16416 B; melst aliases wspec[0]

    const int tid = threadIdx.x;
    const int w   = tid >> 6;               // wave slot = pair-in-block
    const int u   = tid & 63;
    const int P   = blockIdx.x;             // chunk id 0..78
    const int b   = blockIdx.y;
    const int p   = P * PPB + w;            // global frame-pair

    float acc[4];                           // this lane's 4 mel outputs

    if (p < NPAIRS) {
        float2* buf  = wbuf[w];
        float*  spec = wspec[w];

        // load frame pair (reflect pad): z[n] = fr0[n] + i*fr1[n]
        const float* xb = x + (size_t)b * LSAMP;
        const int base = 512 * p - 512;
        #pragma unroll
        for (int j = 0; j < 16; j++) {
            const int i = 64 * j + u;
            buf[i] = make_float2(xb[refl(base + i)], xb[refl(base + i + 256)]);
        }

        float2 z[16];

        // stage 1: DFT16 over a of z[64a+u], twiddle W_1024^{u*k}, store 17u+k
        #pragma unroll
        for (int a = 0; a < 16; a++) z[a] = buf[64*a + u];
        dft16(z);
        {
            float s, c; __sincosf(-(float)M_PI * (float)u * (1.0f/512.0f), &s, &c);
            float2 w1 = make_float2(c, s), wk = w1;
            #pragma unroll
            for (int k = 1; k < 16; k++) { z[k] = cmul(z[k], wk); wk = cmul(wk, w1); }
        }
        #pragma unroll
        for (int k = 0; k < 16; k++) buf[17*u + k] = z[k];

        // stage 2: u -> (k1=u>>2, bp=u&3); DFT16, twiddle W_1024^{16*bp*k}
        const int k1 = u >> 2, bp = u & 3;
        #pragma unroll
        for (int a = 0; a < 16; a++) z[a] = buf[68*a + 17*bp + k1];
        dft16(z);
        {
            float s, c; __sincosf(-(float)M_PI * (float)bp * (1.0f/32.0f), &s, &c);
            float2 w1 = make_float2(c, s), wk = w1;
            #pragma unroll
            for (int k = 1; k < 16; k++) { z[k] = cmul(z[k], wk); wk = cmul(wk, w1); }
        }
        #pragma unroll
        for (int k = 0; k < 16; k++) buf[68*k + 17*bp + k1] = z[k];

        // stage 3: DFT4 over bp for each (k1,k2a); X[k1 + 16*k2a + 256*k2b]
        #pragma unroll
        for (int j = 0; j < 4; j++) {
            const int c = 64*j + u;
            const int kk1 = c & 15, k2a = c >> 4;
            #pragma unroll
            for (int bq = 0; bq < 4; bq++) z[4*j + bq] = buf[68*k2a + 17*bq + kk1];
        }
        #pragma unroll
        for (int j = 0; j < 4; j++) {
            const int kbase = u + 64*j;
            float2 t0=z[4*j], t1=z[4*j+1], t2=z[4*j+2], t3=z[4*j+3];
            float2 A=cadd(t0,t2), B=csub(t0,t2), C=cadd(t1,t3), D=csub(t1,t3);
            buf[kbase]       = cadd(A,C);
            buf[kbase + 256] = make_float2(B.x + D.y, B.y - D.x);
            buf[kbase + 512] = csub(A,C);
            buf[kbase + 768] = make_float2(B.x - D.y, B.y + D.x);
        }

        // unpack two-for-one + magnitude (wave's own spec)
        #pragma unroll
        for (int j = 0; j < 9; j++) {
            const int k = 64*j + u;
            if (k < NFREQ) {
                const int nk = (1024 - k) & 1023;
                float2 Zk = buf[k], Zn = buf[nk];
                float ar = Zk.x + Zn.x, ai = Zk.y - Zn.y;
                float br = Zk.y + Zn.y, bi = Zn.x - Zk.x;
                spec[k]         = 0.5f * sqrtf(ar*ar + ai*ai);
                spec[NFREQ + k] = 0.5f * sqrtf(br*br + bi*bi);
            }
        }

        // sparse mel (fb synthesized from bin edges); lane -> pf, 4 bands
        const int r = u & 31, pf = u >> 5;
        const float* sp = spec + pf * NFREQ;
        #pragma unroll
        for (int i = 0; i < 4; i++) {
            const int mm = 32*i + r;
            const int a = bins.v[mm], bb = bins.v[mm+1], c = bins.v[mm+2];
            float a0 = 0.f;
            if (bb > a) {
                float s = 0.f;
                for (int f = a; f < bb; f++) s = fmaf(sp[f], (float)(f - a), s);
                a0 += s / (float)(bb - a);
            }
            if (c > bb) {
                float s = 0.f;
                for (int f = bb; f < c; f++) s = fmaf(sp[f], (float)(c - f), s);
                a0 += s / (float)(c - bb);
            }
            acc[i] = a0;
            mel[((size_t)b * NFRAMES + 2*p + pf) * NMELS + mm] = a0;
        }
    }
    __syncthreads();                        // all waves done reading their spec

    // stage mel into LDS (aliases wspec[0], which is dead now)
    float* melst = &wspec[0][0];            // 8 frames x 128 = 4096 B <= 4104 B
    if (p < NPAIRS) {
        const int r = u & 31, pf = u >> 5;
        const int fl = 2*w + pf;            // local frame 0..7
        #pragma unroll
        for (int i = 0; i < 4; i++) melst[fl*NMELS + 32*i + r] = acc[i];
    }
    __syncthreads();

    // pcen phase A: chunk EMA-from-zero (t=0 seeds exactly)
    if (tid < NMELS) {
        const int t0 = P * 8;
        const int nf = (NFRAMES - t0 < 8) ? NFRAMES - t0 : 8;
        float s = 0.f;
        for (int f = 0; f < nf; f++) {
            float v = melst[f*NMELS + tid];
            s = (t0 + f == 0) ? v : fmaf(0.975f, s, 0.025f * v);
        }
        S[((size_t)b * NCHUNK + P) * NMELS + tid] = s;
    }
}

// PCEN output: block = (chunk c, batch b), 128 threads = m.
// Inline exact affine prefix over chunk-sums (M_out = D8*M_in + S_c),
// then replay the 8-frame chunk from the exact entry state.
__global__ __launch_bounds__(128)
void pcen_out(const float* __restrict__ mel, const float* __restrict__ S,
              float* __restrict__ out) {
    const int m = threadIdx.x;
    const int c = blockIdx.x;               // 0..78
    const int b = blockIdx.y;

    float D8; { float d = 0.975f; d *= d; d *= d; d *= d; D8 = d; }  // 0.975^8

    const float* Sp = S + (size_t)b * NCHUNK * NMELS + m;
    float M = 0.f;
    for (int cc = 0; cc < c; cc++) M = fmaf(D8, M, Sp[(size_t)cc * NMELS]);

    const int t0 = c * 8;
    const int tend = (t0 + 8 < NFRAMES) ? t0 + 8 : NFRAMES;
    const float* mp = mel + (size_t)b * NFRAMES * NMELS + m;
    float*       op = out + (size_t)b * NFRAMES * NMELS + m;
    for (int t = t0; t < tend; t++) {
        float v = mp[(size_t)t * NMELS];
        M = (t == 0) ? v : fmaf(0.975f, M, 0.025f * v);
        float den = __powf(M + 1e-6f, 0.98f);
        op[(size_t)t * NMELS] = sqrtf(v / den + 2.0f) - 1.41421356237f;
    }
}

extern "C" void kernel_launch(void* const* d_in, const int* in_sizes, int n_in,
                              void* d_out, int out_size, void* d_ws, size_t ws_size,
                              hipStream_t stream) {
    const float* x  = (const float*)d_in[0];   // (32, 160000)
    float* out = (float*)d_out;                // (32, 626, 128)

    float* mel = (float*)d_ws;                               // 32*626*128 f32
    float* S   = mel + (size_t)NBATCH * NFRAMES * NMELS;     // 32*79*128 f32

    // Host-side bin edges, replicating numpy exactly in double.
    Bins bins;
    {
        const double m_max = 2595.0 * log10(1.0 + 8000.0 / 700.0);
        const double step  = m_max / 129.0;
        for (int i = 0; i < NMELS + 2; i++) {
            double mv = (i == NMELS + 1) ? m_max : (double)i * step;
            double f  = 700.0 * (pow(10.0, mv / 2595.0) - 1.0);
            bins.v[i] = (int)floor((double)(NFREQ - 1) * 2.0 * f / 16000.0);
        }
    }

    dim3 grid1(NBLK, NBATCH);
    fft_mel_kernel<<<grid1, 256, 0, stream>>>(x, mel, S, bins);

    dim3 grid2(NCHUNK, NBATCH);
    pcen_out<<<grid2, 128, 0, stream>>>(mel, S, out);
}

// Round 7
// 122.179 us; speedup vs baseline: 1.1951x; 1.0872x over previous
//
#include <hip/hip_runtime.h>
#include <math.h>

#define NMELS   128
#define NFRAMES 626
#define NPAIRS  313
#define NBATCH  32
#define LSAMP   160000
#define NFREQ   513                         // 1024/2 + 1
#define PPB     4                           // frame-pairs per block (1 per wave)
#define NBLK    ((NPAIRS + PPB - 1) / PPB)  // 79
#define NCHUNK  NBLK                        // pcen chunk = 8 frames = 1 block

struct Bins { int v[NMELS + 2]; };          // 130 ints = 520 B kernarg

// reflect-pad index (np.pad mode='reflect', no edge repeat)
__device__ __forceinline__ int refl(int i) {
    if (i < 0) i = -i;
    else if (i >= LSAMP) i = 2 * LSAMP - 2 - i;
    return i;
}

__device__ __forceinline__ float2 cadd(float2 a, float2 b){return make_float2(a.x+b.x, a.y+b.y);}
__device__ __forceinline__ float2 csub(float2 a, float2 b){return make_float2(a.x-b.x, a.y-b.y);}
__device__ __forceinline__ float2 cmul(float2 a, float2 b){
    return make_float2(fmaf(a.x,b.x,-a.y*b.y), fmaf(a.x,b.y,a.y*b.x));
}
__device__ __forceinline__ float2 cmulnegi(float2 a){return make_float2(a.y, -a.x);}   // a * (-i)

// 16-point DFT, natural order in/out, registers only (HW-verified R5/R6).
__device__ __forceinline__ void dft16(float2* z) {
    const float2 W1 = make_float2( 0.92387953251f, -0.38268343236f);
    const float2 W2 = make_float2( 0.70710678119f, -0.70710678119f);
    const float2 W3 = make_float2( 0.38268343236f, -0.92387953251f);
    const float2 W6 = make_float2(-0.70710678119f, -0.70710678119f);
    const float2 W9 = make_float2(-0.92387953251f,  0.38268343236f);
    float2 g[16];
    #pragma unroll
    for (int q = 0; q < 4; q++) {
        float2 t0=z[q], t1=z[4+q], t2=z[8+q], t3=z[12+q];
        float2 A=cadd(t0,t2), B=csub(t0,t2), C=cadd(t1,t3), D=csub(t1,t3);
        g[q]    = cadd(A,C);
        g[4+q]  = make_float2(B.x + D.y, B.y - D.x);
        g[8+q]  = csub(A,C);
        g[12+q] = make_float2(B.x - D.y, B.y + D.x);
    }
    g[4+1] =cmul(g[4+1], W1); g[4+2] =cmul(g[4+2], W2); g[4+3] =cmul(g[4+3], W3);
    g[8+1] =cmul(g[8+1], W2); g[8+2] =cmulnegi(g[8+2]); g[8+3] =cmul(g[8+3], W6);
    g[12+1]=cmul(g[12+1],W3); g[12+2]=cmul(g[12+2],W6);  g[12+3]=cmul(g[12+3],W9);
    #pragma unroll
    for (int r = 0; r < 4; r++) {
        float2 t0=g[4*r], t1=g[4*r+1], t2=g[4*r+2], t3=g[4*r+3];
        float2 A=cadd(t0,t2), B=csub(t0,t2), C=cadd(t1,t3), D=csub(t1,t3);
        z[r]    = cadd(A,C);
        z[r+4]  = make_float2(B.x + D.y, B.y - D.x);
        z[r+8]  = csub(A,C);
        z[r+12] = make_float2(B.x - D.y, B.y + D.x);
    }
}

// 256-thread block = 4 wave-private FFT frame-pairs = 8 frames = 1 pcen chunk.
// Per wave: four-step 1024 = 16x16x4 FFT, 16 pts/lane in regs, in-place LDS
// exchanges in the wave's OWN 8704 B buffer -> no __syncthreads in FFT path.
// spec ALIASES the buffer (unpack register-staged: all reads before writes,
// in-order per-wave DS pipe). LDS = 34.8 KB/block -> 4 blocks/CU.
__global__ __launch_bounds__(256, 4)
void fft_mel_kernel(const float* __restrict__ x, float* __restrict__ mel,
                    float* __restrict__ S, Bins bins) {
    __shared__ float2 wbuf[PPB][1088];      // 34816 B total

    const int tid = threadIdx.x;
    const int w   = tid >> 6;               // wave slot = pair-in-block
    const int u   = tid & 63;
    const int P   = blockIdx.x;             // chunk id 0..78
    const int b   = blockIdx.y;
    const int p   = P * PPB + w;            // global frame-pair

    float acc[4];                           // this lane's 4 mel outputs

    if (p < NPAIRS) {
        float2* buf  = wbuf[w];
        float*  spec = (float*)&wbuf[w][0]; // aliases buf (safe: see unpack)

        // load frame pair (reflect pad): z[n] = fr0[n] + i*fr1[n]
        const float* xb = x + (size_t)b * LSAMP;
        const int base = 512 * p - 512;
        #pragma unroll
        for (int j = 0; j < 16; j++) {
            const int i = 64 * j + u;
            buf[i] = make_float2(xb[refl(base + i)], xb[refl(base + i + 256)]);
        }

        float2 z[16];

        // stage 1: DFT16 over a of z[64a+u], twiddle W_1024^{u*k}, store 17u+k
        #pragma unroll
        for (int a = 0; a < 16; a++) z[a] = buf[64*a + u];
        dft16(z);
        {
            float s, c; __sincosf(-(float)M_PI * (float)u * (1.0f/512.0f), &s, &c);
            float2 w1 = make_float2(c, s), wk = w1;
            #pragma unroll
            for (int k = 1; k < 16; k++) { z[k] = cmul(z[k], wk); wk = cmul(wk, w1); }
        }
        #pragma unroll
        for (int k = 0; k < 16; k++) buf[17*u + k] = z[k];

        // stage 2: u -> (k1=u>>2, bp=u&3); DFT16, twiddle W_1024^{16*bp*k}
        const int k1 = u >> 2, bp = u & 3;
        #pragma unroll
        for (int a = 0; a < 16; a++) z[a] = buf[68*a + 17*bp + k1];
        dft16(z);
        {
            float s, c; __sincosf(-(float)M_PI * (float)bp * (1.0f/32.0f), &s, &c);
            float2 w1 = make_float2(c, s), wk = w1;
            #pragma unroll
            for (int k = 1; k < 16; k++) { z[k] = cmul(z[k], wk); wk = cmul(wk, w1); }
        }
        #pragma unroll
        for (int k = 0; k < 16; k++) buf[68*k + 17*bp + k1] = z[k];

        // stage 3: DFT4 over bp for each (k1,k2a); X[k1 + 16*k2a + 256*k2b]
        #pragma unroll
        for (int j = 0; j < 4; j++) {
            const int c = 64*j + u;
            const int kk1 = c & 15, k2a = c >> 4;
            #pragma unroll
            for (int bq = 0; bq < 4; bq++) z[4*j + bq] = buf[68*k2a + 17*bq + kk1];
        }
        #pragma unroll
        for (int j = 0; j < 4; j++) {
            const int kbase = u + 64*j;
            float2 t0=z[4*j], t1=z[4*j+1], t2=z[4*j+2], t3=z[4*j+3];
            float2 A=cadd(t0,t2), B=csub(t0,t2), C=cadd(t1,t3), D=csub(t1,t3);
            buf[kbase]       = cadd(A,C);
            buf[kbase + 256] = make_float2(B.x + D.y, B.y - D.x);
            buf[kbase + 512] = csub(A,C);
            buf[kbase + 768] = make_float2(B.x - D.y, B.y + D.x);
        }

        // unpack two-for-one + magnitude, REGISTER-STAGED so spec can alias buf:
        // all buf reads complete (into m0/m1) before any spec write is issued.
        float m0[9], m1[9];
        #pragma unroll
        for (int j = 0; j < 9; j++) {
            const int k = 64*j + u;
            if (k <= 512) {
                const int nk = (1024 - k) & 1023;
                float2 Zk = buf[k], Zn = buf[nk];
                float ar = Zk.x + Zn.x, ai = Zk.y - Zn.y;
                float br = Zk.y + Zn.y, bi = Zn.x - Zk.x;
                m0[j] = 0.5f * sqrtf(ar*ar + ai*ai);
                m1[j] = 0.5f * sqrtf(br*br + bi*bi);
            }
        }
        #pragma unroll
        for (int j = 0; j < 9; j++) {
            const int k = 64*j + u;
            if (k <= 512) { spec[k] = m0[j]; spec[NFREQ + k] = m1[j]; }
        }

        // sparse mel (fb synthesized from bin edges); lane -> pf, 4 bands
        const int r = u & 31, pf = u >> 5;
        const float* sp = spec + pf * NFREQ;
        #pragma unroll
        for (int i = 0; i < 4; i++) {
            const int mm = 32*i + r;
            const int a = bins.v[mm], bb = bins.v[mm+1], c = bins.v[mm+2];
            float a0 = 0.f;
            if (bb > a) {
                float s = 0.f;
                for (int f = a; f < bb; f++) s = fmaf(sp[f], (float)(f - a), s);
                a0 += s / (float)(bb - a);
            }
            if (c > bb) {
                float s = 0.f;
                for (int f = bb; f < c; f++) s = fmaf(sp[f], (float)(c - f), s);
                a0 += s / (float)(c - bb);
            }
            acc[i] = a0;
            mel[((size_t)b * NFRAMES + 2*p + pf) * NMELS + mm] = a0;
        }
    }
    __syncthreads();                        // all waves done with their spec

    // stage mel into LDS: upper half of wave-0's region (floats 1088..2112),
    // disjoint from wave-0's spec (floats 0..1025). Dead space post-barrier.
    float* melst = (float*)&wbuf[0][544];   // 1024 floats
    if (p < NPAIRS) {
        const int r = u & 31, pf = u >> 5;
        const int fl = 2*w + pf;            // local frame 0..7
        #pragma unroll
        for (int i = 0; i < 4; i++) melst[fl*NMELS + 32*i + r] = acc[i];
    }
    __syncthreads();

    // pcen phase A: chunk EMA-from-zero (t=0 seeds exactly)
    if (tid < NMELS) {
        const int t0 = P * 8;
        const int nf = (NFRAMES - t0 < 8) ? NFRAMES - t0 : 8;
        float s = 0.f;
        for (int f = 0; f < nf; f++) {
            float v = melst[f*NMELS + tid];
            s = (t0 + f == 0) ? v : fmaf(0.975f, s, 0.025f * v);
        }
        S[((size_t)b * NCHUNK + P) * NMELS + tid] = s;
    }
}

// PCEN phase B: exclusive affine scan over 79 chunks per (b,m).
// M_out = D8*M_in + S_c with D8 = 0.975^8. Compile-time trip count ->
// unrolled, loads pipelined.
__global__ __launch_bounds__(256)
void pcen_scan(const float* __restrict__ S, float* __restrict__ Mstart) {
    const int idx = blockIdx.x * 256 + threadIdx.x;   // 0..4095
    const int m = idx & 127;
    const int b = idx >> 7;
    if (b >= NBATCH) return;

    float D8; { float d = 0.975f; d *= d; d *= d; d *= d; D8 = d; }

    const size_t base = (size_t)b * NCHUNK * NMELS + m;
    float M = 0.f;
    #pragma unroll 8
    for (int c = 0; c < NCHUNK; c++) {
        Mstart[base + (size_t)c * NMELS] = M;
        M = fmaf(D8, M, S[base + (size_t)c * NMELS]);
    }
}

// PCEN phase C: block = (chunk c, batch b), 128 threads = m.
// Replay 8 frames from the exact chunk-entry state. No prefix loop.
__global__ __launch_bounds__(128)
void pcen_out(const float* __restrict__ mel, const float* __restrict__ Mstart,
              float* __restrict__ out) {
    const int m = threadIdx.x;
    const int c = blockIdx.x;               // 0..78
    const int b = blockIdx.y;

    float M = Mstart[((size_t)b * NCHUNK + c) * NMELS + m];

    const int t0 = c * 8;
    const int tend = (t0 + 8 < NFRAMES) ? t0 + 8 : NFRAMES;
    const float* mp = mel + (size_t)b * NFRAMES * NMELS + m;
    float*       op = out + (size_t)b * NFRAMES * NMELS + m;
    #pragma unroll 8
    for (int t = t0; t < tend; t++) {
        float v = mp[(size_t)t * NMELS];
        M = (t == 0) ? v : fmaf(0.975f, M, 0.025f * v);
        float den = __powf(M + 1e-6f, 0.98f);
        op[(size_t)t * NMELS] = sqrtf(v / den + 2.0f) - 1.41421356237f;
    }
}

extern "C" void kernel_launch(void* const* d_in, const int* in_sizes, int n_in,
                              void* d_out, int out_size, void* d_ws, size_t ws_size,
                              hipStream_t stream) {
    const float* x  = (const float*)d_in[0];   // (32, 160000)
    float* out = (float*)d_out;                // (32, 626, 128)

    float* mel    = (float*)d_ws;                              // 32*626*128 f32
    float* S      = mel + (size_t)NBATCH * NFRAMES * NMELS;    // 32*79*128 f32
    float* Mstart = S   + (size_t)NBATCH * NCHUNK * NMELS;     // 32*79*128 f32

    // Host-side bin edges, replicating numpy exactly in double.
    Bins bins;
    {
        const double m_max = 2595.0 * log10(1.0 + 8000.0 / 700.0);
        const double step  = m_max / 129.0;
        for (int i = 0; i < NMELS + 2; i++) {
            double mv = (i == NMELS + 1) ? m_max : (double)i * step;
            double f  = 700.0 * (pow(10.0, mv / 2595.0) - 1.0);
            bins.v[i] = (int)floor((double)(NFREQ - 1) * 2.0 * f / 16000.0);
        }
    }

    dim3 grid1(NBLK, NBATCH);
    fft_mel_kernel<<<grid1, 256, 0, stream>>>(x, mel, S, bins);

    pcen_scan<<<(NBATCH * NMELS + 255) / 256, 256, 0, stream>>>(S, Mstart);

    dim3 grid3(NCHUNK, NBATCH);
    pcen_out<<<grid3, 128, 0, stream>>>(mel, Mstart, out);
}